// Round 1
// baseline (138.695 us; speedup 1.0000x reference)
//
#include <hip/hip_runtime.h>
#include <hip/hip_bf16.h>

#define N 16384
#define D 128
#define BC 64            // columns per block (kernel B)
#define RS 4             // row splits (kernel B)
#define RT 64            // rows per iteration (kernel B)
#define ITERS ((N / RS) / RT)

typedef __attribute__((ext_vector_type(8))) short bf16x8;
typedef __attribute__((ext_vector_type(4))) float f32x4;

#define GLOBAL_AS __attribute__((address_space(1)))
#define LDS_AS __attribute__((address_space(3)))

// ---------------- Kernel A: normalize targets -> bf16 bn ----------------
__global__ __launch_bounds__(256) void knorm(const float* __restrict__ t,
                                             __hip_bfloat16* __restrict__ bn) {
    const int row  = blockIdx.x * 4 + (threadIdx.x >> 6);
    const int lane = threadIdx.x & 63;
    const float2 v = *(const float2*)(t + (size_t)row * D + lane * 2);
    float ss = v.x * v.x + v.y * v.y;
#pragma unroll
    for (int m = 1; m <= 32; m <<= 1) ss += __shfl_xor(ss, m, 64);
    const float inv = rsqrtf(ss);
    __hip_bfloat162 o;
    o.x = __float2bfloat16(v.x * inv);
    o.y = __float2bfloat16(v.y * inv);
    *(__hip_bfloat162*)(bn + (size_t)row * D + lane * 2) = o;
}

// ---------------- Kernel B: fused bn @ bn^T + per-column argmax ----------------
// grid = (N/BC) * RS blocks, 256 threads (4 waves).
// Block (ct, s): columns [ct*BC, ct*BC+64), rows [s*N/RS, (s+1)*N/RS).
// Wave w handles rows (iter*64 + w*16 .. +16) x all 64 columns.
__global__ __launch_bounds__(256) void kargmax(const __hip_bfloat16* __restrict__ bn,
                                               float* __restrict__ pval,
                                               int* __restrict__ pidx) {
    __shared__ __align__(16) char lds[RT * D * 2];   // 16 KB A-tile
    __shared__ float sval[4][BC];
    __shared__ int   sidx[4][BC];

    const int tid  = threadIdx.x;
    const int lane = tid & 63;
    const int w    = tid >> 6;
    const int ct   = blockIdx.x % (N / BC);
    const int s    = blockIdx.x / (N / BC);
    const int j0   = ct * BC;
    const int rbase = s * (N / RS);

    const int lr = lane & 15;   // row/col within 16-tile
    const int lk = lane >> 4;   // K-subgroup 0..3

    // persistent B fragments: 64 cols x 128 K  (4 col-subtiles x 4 K-steps)
    bf16x8 fb[4][4];
#pragma unroll
    for (int cs = 0; cs < 4; ++cs)
#pragma unroll
        for (int ks = 0; ks < 4; ++ks)
            fb[cs][ks] = *(const bf16x8*)(bn + (size_t)(j0 + cs * 16 + lr) * D + ks * 32 + lk * 8);

    float mv[4];
    int   mi[4];
#pragma unroll
    for (int cs = 0; cs < 4; ++cs) { mv[cs] = -1e30f; mi[cs] = 0; }

    const char* bnb = (const char*)bn;

    for (int it = 0; it < ITERS; ++it) {
        const int r0 = rbase + it * RT;
        __syncthreads();   // prior iteration's LDS reads complete
        // stage 64 rows x 256B = 16 KB; source pre-swizzled so LDS dest stays linear
#pragma unroll
        for (int u = 0; u < 4; ++u) {
            const int chunk = u * 256 + tid;        // 16B chunk id 0..1023
            const int row   = chunk >> 4;           // 0..63
            const int cbp   = chunk & 15;           // dest 16B column-chunk
            const int cb    = cbp ^ (row & 7);      // swizzled source chunk
            const void* src = bnb + (size_t)(r0 + row) * 256 + cb * 16;
            __builtin_amdgcn_global_load_lds((const GLOBAL_AS void*)src,
                                             (LDS_AS void*)(lds + chunk * 16), 16, 0, 0);
        }
        __syncthreads();   // staging complete

        f32x4 acc[4];
#pragma unroll
        for (int cs = 0; cs < 4; ++cs) acc[cs] = (f32x4){0.f, 0.f, 0.f, 0.f};

        const int arow = w * 16 + lr;
        bf16x8 fa[4];
#pragma unroll
        for (int ks = 0; ks < 4; ++ks) {
            const int cb = (ks * 4 + lk) ^ (arow & 7);
            fa[ks] = *(const bf16x8*)(lds + arow * 256 + cb * 16);
        }
#pragma unroll
        for (int cs = 0; cs < 4; ++cs)
#pragma unroll
            for (int ks = 0; ks < 4; ++ks)
                acc[cs] = __builtin_amdgcn_mfma_f32_16x16x32_bf16(fa[ks], fb[cs][ks], acc[cs], 0, 0, 0);

        // running argmax update (C layout: col = lane&15, row = (lane>>4)*4 + reg)
        const int ibase = r0 + w * 16 + lk * 4;
#pragma unroll
        for (int cs = 0; cs < 4; ++cs) {
            const int col = j0 + cs * 16 + lr;
#pragma unroll
            for (int r = 0; r < 4; ++r) {
                float v = acc[cs][r];
                const int i = ibase + r;
                if (i == col) v -= 1.0f;             // replicate sim - eye exactly
                if (v > mv[cs]) { mv[cs] = v; mi[cs] = i; }   // strict > keeps lowest i
            }
        }
    }

    // reduce across the 4 row-groups within the wave (lanes l, l^16, l^32, l^48 share a column)
#pragma unroll
    for (int cs = 0; cs < 4; ++cs) {
#pragma unroll
        for (int m = 16; m <= 32; m <<= 1) {
            const float ov = __shfl_xor(mv[cs], m, 64);
            const int   oi = __shfl_xor(mi[cs], m, 64);
            if (ov > mv[cs] || (ov == mv[cs] && oi < mi[cs])) { mv[cs] = ov; mi[cs] = oi; }
        }
    }
    if (lane < 16) {
#pragma unroll
        for (int cs = 0; cs < 4; ++cs) {
            sval[w][cs * 16 + lr] = mv[cs];
            sidx[w][cs * 16 + lr] = mi[cs];
        }
    }
    __syncthreads();
    // merge the 4 waves' partials (tie -> smaller row index)
    if (tid < BC) {
        float v = sval[0][tid];
        int   i = sidx[0][tid];
#pragma unroll
        for (int w2 = 1; w2 < 4; ++w2) {
            const float ov = sval[w2][tid];
            const int   oi = sidx[w2][tid];
            if (ov > v || (ov == v && oi < i)) { v = ov; i = oi; }
        }
        pval[(size_t)s * N + j0 + tid] = v;
        pidx[(size_t)s * N + j0 + tid] = i;
    }
}

// ---------------- Kernel C: merge splits + hinge loss per row ----------------
__global__ __launch_bounds__(256) void kloss(const float* __restrict__ q,
                                             const float* __restrict__ t,
                                             const float* __restrict__ pval,
                                             const int* __restrict__ pidx,
                                             float* __restrict__ bsum) {
    const int j    = blockIdx.x * 4 + (threadIdx.x >> 6);
    const int lane = threadIdx.x & 63;

    float v = pval[j];
    int   idx = pidx[j];
#pragma unroll
    for (int s = 1; s < RS; ++s) {
        const float ov = pval[(size_t)s * N + j];
        const int   oi = pidx[(size_t)s * N + j];
        if (ov > v || (ov == v && oi < idx)) { v = ov; idx = oi; }
    }

    const float2 qv = *(const float2*)(q + (size_t)j * D + lane * 2);
    const float2 tv = *(const float2*)(t + (size_t)j * D + lane * 2);
    const float2 wv = *(const float2*)(t + (size_t)idx * D + lane * 2);
    float qq = qv.x * qv.x + qv.y * qv.y;
    float tt = tv.x * tv.x + tv.y * tv.y;
    float ww = wv.x * wv.x + wv.y * wv.y;
    float qt = qv.x * tv.x + qv.y * tv.y;
    float qw = qv.x * wv.x + qv.y * wv.y;
#pragma unroll
    for (int m = 1; m <= 32; m <<= 1) {
        qq += __shfl_xor(qq, m, 64);
        tt += __shfl_xor(tt, m, 64);
        ww += __shfl_xor(ww, m, 64);
        qt += __shfl_xor(qt, m, 64);
        qw += __shfl_xor(qw, m, 64);
    }
    const float pos = qt * rsqrtf(qq * tt);
    const float neg = qw * rsqrtf(qq * ww);
    const float l   = fmaxf(0.f, 1.0f - pos + neg);

    __shared__ float ls[4];
    if (lane == 0) ls[threadIdx.x >> 6] = l;
    __syncthreads();
    if (threadIdx.x == 0) bsum[blockIdx.x] = ls[0] + ls[1] + ls[2] + ls[3];
}

// ---------------- Kernel D: deterministic final mean ----------------
__global__ __launch_bounds__(256) void kfinal(const float* __restrict__ bsum,
                                              float* __restrict__ out) {
    float sum = 0.f;
    for (int i = threadIdx.x; i < N / 4; i += 256) sum += bsum[i];
#pragma unroll
    for (int m = 1; m <= 32; m <<= 1) sum += __shfl_xor(sum, m, 64);
    __shared__ float ws2[4];
    if ((threadIdx.x & 63) == 0) ws2[threadIdx.x >> 6] = sum;
    __syncthreads();
    if (threadIdx.x == 0) out[0] = (ws2[0] + ws2[1] + ws2[2] + ws2[3]) * (1.0f / N);
}

extern "C" void kernel_launch(void* const* d_in, const int* in_sizes, int n_in,
                              void* d_out, int out_size, void* d_ws, size_t ws_size,
                              hipStream_t stream) {
    const float* q = (const float*)d_in[0];
    const float* t = (const float*)d_in[1];
    char* ws = (char*)d_ws;

    __hip_bfloat16* bn = (__hip_bfloat16*)ws;                       // 4 MB
    float* pval = (float*)(ws + (size_t)N * D * 2);                 // 256 KB
    int*   pidx = (int*)(ws + (size_t)N * D * 2 + (size_t)RS * N * 4);       // 256 KB
    float* bsum = (float*)(ws + (size_t)N * D * 2 + (size_t)2 * RS * N * 4); // 16 KB

    knorm<<<dim3(N / 4), dim3(256), 0, stream>>>(t, bn);
    kargmax<<<dim3((N / BC) * RS), dim3(256), 0, stream>>>(bn, pval, pidx);
    kloss<<<dim3(N / 4), dim3(256), 0, stream>>>(q, t, pval, pidx, bsum);
    kfinal<<<dim3(1), dim3(256), 0, stream>>>(bsum, (float*)d_out);
}

// Round 2
// 103.123 us; speedup vs baseline: 1.3450x; 1.3450x over previous
//
#include <hip/hip_runtime.h>
#include <hip/hip_bf16.h>

#define N 16384
#define D 128
#define RS 16                        // row splits
#define CT 32                        // col tiles (N / 512)
#define ROWS_PER_SPLIT (N / RS)      // 1024
#define ITERS (ROWS_PER_SPLIT / 16)  // 64

typedef __attribute__((ext_vector_type(8))) short bf16x8;
typedef __attribute__((ext_vector_type(4))) float f32x4;

// ---------------- Kernel A: normalize targets -> bf16 bn ----------------
__global__ __launch_bounds__(256) void knorm(const float* __restrict__ t,
                                             __hip_bfloat16* __restrict__ bn) {
    const int row  = blockIdx.x * 4 + (threadIdx.x >> 6);
    const int lane = threadIdx.x & 63;
    const float2 v = *(const float2*)(t + (size_t)row * D + lane * 2);
    float ss = v.x * v.x + v.y * v.y;
#pragma unroll
    for (int m = 1; m <= 32; m <<= 1) ss += __shfl_xor(ss, m, 64);
    const float inv = rsqrtf(ss);
    __hip_bfloat162 o;
    o.x = __float2bfloat16(v.x * inv);
    o.y = __float2bfloat16(v.y * inv);
    *(__hip_bfloat162*)(bn + (size_t)row * D + lane * 2) = o;
}

// ---------------- Kernel B: fused bn @ bn^T + per-column group-argmax ----------------
// grid = CT * RS = 512 blocks, 4 waves. Wave w: cols [ct*512 + w*128, +128),
// rows [s*1024, (s+1)*1024) in 64 iterations of 16 rows. No LDS, no barriers.
// Tracks per-column (max of each 4-row group, group base row).
__global__ __launch_bounds__(256, 2) void kargmax(const __hip_bfloat16* __restrict__ bn,
                                                  float* __restrict__ pval,
                                                  int* __restrict__ pcode) {
    const int tid  = threadIdx.x;
    const int lane = tid & 63;
    const int w    = tid >> 6;
    const int ct   = blockIdx.x & (CT - 1);
    const int s    = blockIdx.x >> 5;
    const int j0w  = ct * 512 + w * 128;
    const int rbase = s * ROWS_PER_SPLIT;

    const int lr = lane & 15;
    const int lk = lane >> 4;

    // persistent B fragments: 128 cols x 128 K
    bf16x8 fb[8][4];
#pragma unroll
    for (int cs = 0; cs < 8; ++cs)
#pragma unroll
        for (int ks = 0; ks < 4; ++ks)
            fb[cs][ks] = *(const bf16x8*)(bn + (size_t)(j0w + cs * 16 + lr) * D + ks * 32 + lk * 8);

    const char* aptr = (const char*)bn + (size_t)(rbase + lr) * 256 + lk * 16;

    float mv[8];
    int   mc[8];
#pragma unroll
    for (int cs = 0; cs < 8; ++cs) { mv[cs] = -1e30f; mc[cs] = 0; }
    int rowc = rbase + lk * 4;

    const f32x4 z4 = {0.f, 0.f, 0.f, 0.f};
    bf16x8 faA[4], faB[4];

#define LOADF(buf, itv) do {                                        \
    const char* p_ = aptr + (size_t)(itv) * 4096;                   \
    buf[0] = *(const bf16x8*)(p_);                                  \
    buf[1] = *(const bf16x8*)(p_ + 64);                             \
    buf[2] = *(const bf16x8*)(p_ + 128);                            \
    buf[3] = *(const bf16x8*)(p_ + 192); } while (0)

#define COMPUTEF(buf, itv) do {                                                             \
    f32x4 acc[8];                                                                           \
    _Pragma("unroll")                                                                       \
    for (int cs = 0; cs < 8; ++cs) {                                                        \
        acc[cs] = __builtin_amdgcn_mfma_f32_16x16x32_bf16(buf[0], fb[cs][0], z4, 0, 0, 0);  \
        _Pragma("unroll")                                                                   \
        for (int ks = 1; ks < 4; ++ks)                                                      \
            acc[cs] = __builtin_amdgcn_mfma_f32_16x16x32_bf16(buf[ks], fb[cs][ks], acc[cs], 0, 0, 0); \
    }                                                                                       \
    const int r0_ = rbase + (itv) * 16;                                                     \
    if ((unsigned)(r0_ - j0w) < 128u) {                                                     \
        _Pragma("unroll")                                                                   \
        for (int cs = 0; cs < 8; ++cs)                                                      \
            if (r0_ == j0w + cs * 16) {                                                     \
                _Pragma("unroll")                                                           \
                for (int r = 0; r < 4; ++r)                                                 \
                    acc[cs][r] = (lk * 4 + r == lr) ? acc[cs][r] - 1.0f : acc[cs][r];       \
            }                                                                               \
    }                                                                                       \
    _Pragma("unroll")                                                                       \
    for (int cs = 0; cs < 8; ++cs) {                                                        \
        const float g_ = fmaxf(fmaxf(acc[cs][0], acc[cs][1]), fmaxf(acc[cs][2], acc[cs][3])); \
        if (g_ > mv[cs]) { mv[cs] = g_; mc[cs] = rowc; }                                    \
    }                                                                                       \
    rowc += 16; } while (0)

    LOADF(faA, 0);
    for (int it2 = 0; it2 < ITERS; it2 += 2) {
        LOADF(faB, it2 + 1);
        COMPUTEF(faA, it2);
        LOADF(faA, it2 + 2);   // final overshoot reads into pval region — allocated, unused
        COMPUTEF(faB, it2 + 1);
    }
#undef LOADF
#undef COMPUTEF

    // reduce across the 4 lk groups (lanes l, l^16, l^32, l^48 share a column)
#pragma unroll
    for (int cs = 0; cs < 8; ++cs) {
        float v = mv[cs];
        int   c = mc[cs];
#pragma unroll
        for (int m = 16; m <= 32; m <<= 1) {
            const float ov = __shfl_xor(v, m, 64);
            const int   oc = __shfl_xor(c, m, 64);
            if (ov > v || (ov == v && oc < c)) { v = ov; c = oc; }
        }
        if (lane < 16) {
            pval[(size_t)s * N + j0w + cs * 16 + lr]  = v;
            pcode[(size_t)s * N + j0w + cs * 16 + lr] = c;
        }
    }
}

// ---------------- Kernel C: merge splits, re-rank 4 candidates in fp32, hinge ----------------
__global__ __launch_bounds__(256) void kloss(const float* __restrict__ q,
                                             const float* __restrict__ t,
                                             const float* __restrict__ pval,
                                             const int* __restrict__ pcode,
                                             float* __restrict__ bsum) {
    const int j    = blockIdx.x * 4 + (threadIdx.x >> 6);
    const int lane = threadIdx.x & 63;

    // merge the RS split winners (lane s holds split s)
    float v = -1e30f;
    int   c = 0;
    if (lane < RS) { v = pval[(size_t)lane * N + j]; c = pcode[(size_t)lane * N + j]; }
#pragma unroll
    for (int m = 1; m <= 8; m <<= 1) {
        const float ov = __shfl_xor(v, m, 64);
        const int   oc = __shfl_xor(c, m, 64);
        if (ov > v || (ov == v && oc < c)) { v = ov; c = oc; }
    }
    c = __shfl(c, 0, 64);

    const float2 qv = *(const float2*)(q + (size_t)j * D + lane * 2);
    const float2 tv = *(const float2*)(t + (size_t)j * D + lane * 2);
    float qq = qv.x * qv.x + qv.y * qv.y;
    float tt = tv.x * tv.x + tv.y * tv.y;
    float qt = qv.x * tv.x + qv.y * tv.y;
    float ww[4], wt[4], qw[4];
#pragma unroll
    for (int r = 0; r < 4; ++r) {
        const float2 wv = *(const float2*)(t + (size_t)(c + r) * D + lane * 2);
        ww[r] = wv.x * wv.x + wv.y * wv.y;
        wt[r] = wv.x * tv.x + wv.y * tv.y;
        qw[r] = wv.x * qv.x + wv.y * qv.y;
    }
#pragma unroll
    for (int m = 1; m <= 32; m <<= 1) {
        qq += __shfl_xor(qq, m, 64);
        tt += __shfl_xor(tt, m, 64);
        qt += __shfl_xor(qt, m, 64);
#pragma unroll
        for (int r = 0; r < 4; ++r) {
            ww[r] += __shfl_xor(ww[r], m, 64);
            wt[r] += __shfl_xor(wt[r], m, 64);
            qw[r] += __shfl_xor(qw[r], m, 64);
        }
    }
    const float pos = qt * rsqrtf(qq * tt);
    float best = -1e30f, neg = 0.f;
#pragma unroll
    for (int r = 0; r < 4; ++r) {
        float cr = wt[r] * rsqrtf(ww[r] * tt);
        if (c + r == j) cr -= 1.0f;              // diag candidate, matches sim - eye
        if (cr > best) { best = cr; neg = qw[r] * rsqrtf(qq * ww[r]); }
    }
    const float l = fmaxf(0.f, 1.0f - pos + neg);

    __shared__ float ls[4];
    if (lane == 0) ls[threadIdx.x >> 6] = l;
    __syncthreads();
    if (threadIdx.x == 0) bsum[blockIdx.x] = ls[0] + ls[1] + ls[2] + ls[3];
}

// ---------------- Kernel D: deterministic final mean ----------------
__global__ __launch_bounds__(256) void kfinal(const float* __restrict__ bsum,
                                              float* __restrict__ out) {
    float sum = 0.f;
    for (int i = threadIdx.x; i < N / 4; i += 256) sum += bsum[i];
#pragma unroll
    for (int m = 1; m <= 32; m <<= 1) sum += __shfl_xor(sum, m, 64);
    __shared__ float ws2[4];
    if ((threadIdx.x & 63) == 0) ws2[threadIdx.x >> 6] = sum;
    __syncthreads();
    if (threadIdx.x == 0) out[0] = (ws2[0] + ws2[1] + ws2[2] + ws2[3]) * (1.0f / N);
}

extern "C" void kernel_launch(void* const* d_in, const int* in_sizes, int n_in,
                              void* d_out, int out_size, void* d_ws, size_t ws_size,
                              hipStream_t stream) {
    const float* q = (const float*)d_in[0];
    const float* t = (const float*)d_in[1];
    char* ws = (char*)d_ws;

    __hip_bfloat16* bn = (__hip_bfloat16*)ws;                          // 4 MB (must stay first)
    float* pval = (float*)(ws + (size_t)N * D * 2);                    // 1 MB
    int*   pcode = (int*)(ws + (size_t)N * D * 2 + (size_t)RS * N * 4);// 1 MB
    float* bsum = (float*)(ws + (size_t)N * D * 2 + (size_t)2 * RS * N * 4); // 16 KB

    knorm<<<dim3(N / 4), dim3(256), 0, stream>>>(t, bn);
    kargmax<<<dim3(CT * RS), dim3(256), 0, stream>>>(bn, pval, pcode);
    kloss<<<dim3(N / 4), dim3(256), 0, stream>>>(q, t, pval, pcode, bsum);
    kfinal<<<dim3(1), dim3(256), 0, stream>>>(bsum, (float*)d_out);
}